// Round 15
// baseline (220.201 us; speedup 1.0000x reference)
//
#include <hip/hip_runtime.h>

#define N_OBJ 1024
#define E_P   32768

typedef float f32x4 __attribute__((ext_vector_type(4)));
typedef short bf16x8 __attribute__((ext_vector_type(8)));
typedef unsigned short u16x4 __attribute__((ext_vector_type(4)));

__device__ __forceinline__ unsigned short f2bf(float f) {
    unsigned u = __float_as_uint(f);
    u = u + 0x7FFFu + ((u >> 16) & 1u);   // RNE
    return (unsigned short)(u >> 16);
}
__device__ __forceinline__ float bf2f(unsigned short u) {
    return __uint_as_float(((unsigned)u) << 16);
}

// ---- copy split (f32x4 units): total = 1024*1024*64/4 = 16777216 ----
#define OFF_A    0
#define LEN_A    5242880
#define OFF_B    (OFF_A + LEN_A)
#define LEN_B    4194304
#define OFF_SEG  (OFF_B + LEN_B)
#define LEN_SEG  4194304
#define OFF_OUT  (OFF_SEG + LEN_SEG)
#define LEN_OUT  3145728

// Non-temporal copy with DEEP read MLP: 8 independent loads in flight per lane
// (128 B/lane outstanding). At ~3 waves/SIMD this gives ~24 KB/CU ≈ 6 MB chip-wide
// outstanding reads — enough to saturate HBM even at low occupancy.
__device__ __forceinline__ void copy_nt(const f32x4* __restrict__ src,
                                        f32x4* __restrict__ dst,
                                        int off, int len, int nb, int cb) {
    int stride = nb * 256;
    int i = off + cb * 256 + threadIdx.x;
    int end = off + len;
    for (; i + 7 * stride < end; i += 8 * stride) {
        f32x4 v0 = __builtin_nontemporal_load(&src[i]);
        f32x4 v1 = __builtin_nontemporal_load(&src[i + stride]);
        f32x4 v2 = __builtin_nontemporal_load(&src[i + 2 * stride]);
        f32x4 v3 = __builtin_nontemporal_load(&src[i + 3 * stride]);
        f32x4 v4 = __builtin_nontemporal_load(&src[i + 4 * stride]);
        f32x4 v5 = __builtin_nontemporal_load(&src[i + 5 * stride]);
        f32x4 v6 = __builtin_nontemporal_load(&src[i + 6 * stride]);
        f32x4 v7 = __builtin_nontemporal_load(&src[i + 7 * stride]);
        __builtin_nontemporal_store(v0, &dst[i]);
        __builtin_nontemporal_store(v1, &dst[i + stride]);
        __builtin_nontemporal_store(v2, &dst[i + 2 * stride]);
        __builtin_nontemporal_store(v3, &dst[i + 3 * stride]);
        __builtin_nontemporal_store(v4, &dst[i + 4 * stride]);
        __builtin_nontemporal_store(v5, &dst[i + 5 * stride]);
        __builtin_nontemporal_store(v6, &dst[i + 6 * stride]);
        __builtin_nontemporal_store(v7, &dst[i + 7 * stride]);
    }
    for (; i < end; i += stride) {
        f32x4 a = __builtin_nontemporal_load(&src[i]);
        __builtin_nontemporal_store(a, &dst[i]);
    }
}

__global__ __launch_bounds__(256) void k_zero(int* __restrict__ counts) {
    ((int4*)counts)[threadIdx.x] = make_int4(0, 0, 0, 0);
}

// ================= k_a: transposes + featsb + pairs/hist/rank + bbg(bf16) + HS-zero + nt-copy =================
// grid 3456: bid%3==2 -> copy (1152); else job = (bid/3)*2 + bid%3 (0..2303)
__global__ __launch_bounds__(256) void k_a(const float* __restrict__ W1,
                                           const float* __restrict__ W2,
                                           const float* __restrict__ feats,
                                           const int* __restrict__ pairs,
                                           const float* __restrict__ bb,
                                           unsigned short* __restrict__ w1pqT,
                                           unsigned short* __restrict__ w1cT,
                                           unsigned short* __restrict__ w2T,
                                           unsigned short* __restrict__ featsb,
                                           float* __restrict__ out_pairs,
                                           int* __restrict__ counts,
                                           int* __restrict__ rank,
                                           unsigned short* __restrict__ bbgb,
                                           f32x4* __restrict__ hs4,
                                           const f32x4* __restrict__ csrc,
                                           f32x4* __restrict__ cdst) {
    int bid = blockIdx.x, tid = threadIdx.x;
    if ((bid % 3) == 2) { copy_nt(csrc, cdst, OFF_A, LEN_A, 1152, bid / 3); return; }
    int job = (bid / 3) * 2 + (bid % 3);
    if (job >= 2240) {                 // HS zero: 64 blocks x 4096 f32x4
        int blk = job - 2240;
        f32x4 z = {0.f, 0.f, 0.f, 0.f};
        f32x4* p = hs4 + (size_t)blk * 4096 + tid;
        #pragma unroll
        for (int it = 0; it < 16; ++it) p[it * 256] = z;
        return;
    }
    if (job >= 2112) {                 // bbg gather -> bf16
        int e = (job - 2112) * 256 + tid;
        int sub = pairs[2 * e], obj = pairs[2 * e + 1];
        const f32x4* src = (const f32x4*)&bb[((size_t)sub * 1024 + (size_t)obj) * 64];
        u16x4* dst = (u16x4*)&bbgb[(size_t)e * 64];
        #pragma unroll
        for (int i = 0; i < 16; ++i) {
            f32x4 v = __builtin_nontemporal_load(&src[i]);
            u16x4 o = { f2bf(v.x), f2bf(v.y), f2bf(v.z), f2bf(v.w) };
            dst[i] = o;
        }
        return;
    }
    if (job >= 1856) {                 // pairs passthrough + histogram + rank
        int i = (job - 1856) * 256 + tid;
        out_pairs[i] = (float)pairs[i];
        if (i < E_P) rank[i] = atomicAdd(&counts[pairs[2 * i]], 1);
        return;
    }
    if (job >= 1600) {                 // featsb straight convert
        int base = (job - 1600) * 2048 + tid * 8;
        float4 v0 = *(const float4*)&feats[base];
        float4 v1 = *(const float4*)&feats[base + 4];
        u16x4 o0 = { f2bf(v0.x), f2bf(v0.y), f2bf(v0.z), f2bf(v0.w) };
        u16x4 o1 = { f2bf(v1.x), f2bf(v1.y), f2bf(v1.z), f2bf(v1.w) };
        *(u16x4*)&featsb[base] = o0;
        *(u16x4*)&featsb[base + 4] = o1;
        return;
    }
    const float* in; unsigned short* out;
    int LDI, LDO, r0, c0, nbase, kbase;
    if (job < 1024) {                  // W1[0:1024] -> w1pqT [2048][512]
        r0 = (job >> 5) * 32; c0 = (job & 31) * 32;
        in = W1; LDI = 1024; out = w1pqT; LDO = 512;
        nbase = c0 + (r0 >= 512 ? 1024 : 0); kbase = r0 & 511;
    } else if (job < 1088) {           // W1[1024:1088] -> w1cT [1024][64]
        int t = job - 1024; r0 = 1024 + (t >> 5) * 32; c0 = (t & 31) * 32;
        in = W1; LDI = 1024; out = w1cT; LDO = 64;
        nbase = c0; kbase = r0 - 1024;
    } else {                           // W2 [1024][512] -> w2T [512][1024]
        int t = job - 1088; r0 = (t >> 4) * 32; c0 = (t & 15) * 32;
        in = W2; LDI = 512; out = w2T; LDO = 1024;
        nbase = c0; kbase = r0;
    }
    __shared__ float lds[32][33];
    int ti = tid >> 3, tj = (tid & 7) * 4;
    float4 v = *(const float4*)&in[(size_t)(r0 + ti) * LDI + c0 + tj];
    lds[ti][tj] = v.x; lds[ti][tj + 1] = v.y; lds[ti][tj + 2] = v.z; lds[ti][tj + 3] = v.w;
    __syncthreads();
    int oc = tid >> 3, oj = (tid & 7) * 4;
    u16x4 o = { f2bf(lds[oj][oc]), f2bf(lds[oj + 1][oc]),
                f2bf(lds[oj + 2][oc]), f2bf(lds[oj + 3][oc]) };
    *(u16x4*)&out[(size_t)(nbase + oc) * LDO + kbase + oj] = o;
}

// ================= k_b: brec-build + scatter + PQ GEMM (Q -> bf16) + nt-copy =================
// grid 1923: bid%3<2 -> copy (1282); bid%3==2 -> role = bid/3 (0..640)
__global__ __launch_bounds__(256) void k_b(const int* __restrict__ counts,
                                           const int* __restrict__ rank,
                                           const int* __restrict__ pairs,
                                           int* __restrict__ csr_obj,
                                           int* __restrict__ csr_e,
                                           unsigned* __restrict__ brec,
                                           int* __restrict__ bcnt,
                                           const unsigned short* __restrict__ featsb,
                                           const unsigned short* __restrict__ w1pqT,
                                           const float* __restrict__ b1,
                                           float* __restrict__ P,
                                           unsigned short* __restrict__ Qb,
                                           const f32x4* __restrict__ csrc,
                                           f32x4* __restrict__ cdst) {
    int bid = blockIdx.x, tid = threadIdx.x;
    if ((bid % 3) < 2) { copy_nt(csrc, cdst, OFF_B, LEN_B, 1282, (bid / 3) * 2 + (bid % 3)); return; }
    int role = bid / 3;

    if (role >= 129) {                 // ---- PQ GEMM tile ----
        int job = role - 129;
        int m0 = (job >> 5) * 64, n0 = (job & 31) * 64;
        int w = tid >> 6, l = tid & 63;
        int ln = l & 15, kb = (l >> 4) * 8;
        int row = m0 + w * 16 + ln;
        f32x4 acc[4] = {};
        for (int k0 = 0; k0 < 512; k0 += 32) {
            bf16x8 a = *(const bf16x8*)&featsb[(size_t)row * 512 + k0 + kb];
            #pragma unroll
            for (int f = 0; f < 4; ++f) {
                bf16x8 b = *(const bf16x8*)&w1pqT[(size_t)(n0 + f * 16 + ln) * 512 + k0 + kb];
                acc[f] = __builtin_amdgcn_mfma_f32_16x16x32_bf16(a, b, acc[f], 0, 0, 0);
            }
        }
        int mr = m0 + w * 16 + (l >> 4) * 4;
        if (n0 < 1024) {
            #pragma unroll
            for (int f = 0; f < 4; ++f) {
                int n = n0 + f * 16 + ln;
                float b1v = b1[n];
                #pragma unroll
                for (int r = 0; r < 4; ++r)
                    P[(size_t)(mr + r) * 1024 + n] = acc[f][r] + b1v;
            }
        } else {
            #pragma unroll
            for (int f = 0; f < 4; ++f) {
                int n = n0 - 1024 + f * 16 + ln;
                #pragma unroll
                for (int r = 0; r < 4; ++r)
                    Qb[(size_t)(mr + r) * 1024 + n] = f2bf(acc[f][r]);
            }
        }
        return;
    }

    // ---- roles 0..128: redundant exclusive scan of counts in LDS ----
    __shared__ int sbuf[2][256];
    __shared__ int soff[1024];
    int c[4]; int s = 0;
    #pragma unroll
    for (int i = 0; i < 4; ++i) { c[i] = counts[tid * 4 + i]; s += c[i]; }
    sbuf[0][tid] = s;
    __syncthreads();
    int sel = 0;
    for (int d = 1; d < 256; d <<= 1) {
        int v = sbuf[sel][tid];
        if (tid >= d) v += sbuf[sel][tid - d];
        sbuf[sel ^ 1][tid] = v;
        sel ^= 1;
        __syncthreads();
    }
    int base = sbuf[sel][tid] - s;
    int run = base;
    #pragma unroll
    for (int i = 0; i < 4; ++i) { soff[tid * 4 + i] = run; run += c[i]; }
    __syncthreads();

    if (role >= 1) {                   // ---- scatter (no atomics) ----
        int e = (role - 1) * 256 + tid;
        int sub = pairs[2 * e];
        int pos = soff[sub] + rank[e];
        csr_obj[pos] = pairs[2 * e + 1];
        csr_e[pos] = e;
        return;
    }

    // ---- role 0: batch-32 records ----
    int nb[4]; int t = 0;
    #pragma unroll
    for (int i = 0; i < 4; ++i) { nb[i] = (c[i] + 31) >> 5; t += nb[i]; }
    __syncthreads();
    sbuf[0][tid] = t;
    __syncthreads();
    sel = 0;
    for (int d = 1; d < 256; d <<= 1) {
        int v = sbuf[sel][tid];
        if (tid >= d) v += sbuf[sel][tid - d];
        sbuf[sel ^ 1][tid] = v;
        sel ^= 1;
        __syncthreads();
    }
    int bpos = sbuf[sel][tid] - t;
    int run2 = base;
    #pragma unroll
    for (int i = 0; i < 4; ++i) {
        int seg = tid * 4 + i;
        for (int k = 0; k < nb[i]; ++k) {
            int st = run2 + k * 32;
            int cnt = c[i] - k * 32; if (cnt > 32) cnt = 32;
            brec[bpos++] = (unsigned)st | ((unsigned)seg << 16) | ((unsigned)(cnt - 1) << 26);
        }
        run2 += c[i];
    }
    if (tid == 255) bcnt[0] = bpos;
}

// ================= k_seg: XCD-pinned quarters + bf16 Q/bbg + nt-copy =================
// grid 12288 = 8*1536. x=bid&7 -> XCD; k=bid>>3.
__global__ __launch_bounds__(256) void k_seg(const int* __restrict__ csr_obj,
                                             const int* __restrict__ csr_e,
                                             const unsigned* __restrict__ brec,
                                             const int* __restrict__ bcnt,
                                             const unsigned short* __restrict__ bbgb,
                                             const unsigned short* __restrict__ w1cT,
                                             const float* __restrict__ P,
                                             const unsigned short* __restrict__ Qb,
                                             float* __restrict__ HS,
                                             const f32x4* __restrict__ csrc,
                                             f32x4* __restrict__ cdst) {
    int bid = blockIdx.x, tid = threadIdx.x;
    int x = bid & 7, k = bid >> 3;
    if (k >= 1024) { copy_nt(csrc, cdst, OFF_SEG, LEN_SEG, 4096, (k - 1024) * 8 + x); return; }
    int qd = x >> 1;
    int b = k * 2 + (x & 1);
    if (b >= bcnt[0]) return;
    unsigned rec = brec[b];
    const int start = rec & 0xFFFF;
    const int seg = (rec >> 16) & 0x3FF;
    const int n = ((rec >> 26) & 31) + 1;

    const int w = tid >> 6, l = tid & 63;
    const int ln = l & 15, g4 = l >> 4, kb = g4 * 8;
    const int cbase = qd * 256;
    const int wbase = cbase + w * 64;

    __shared__ unsigned short qs[32][264];

    {
        int p = tid >> 3, j = tid & 7;
        if (p < n) {
            int op = csr_obj[start + p];
            const uint4* qrow = (const uint4*)&Qb[(size_t)op * 1024 + cbase];
            #pragma unroll
            for (int i = 0; i < 4; ++i) {
                uint4 v = qrow[j * 4 + i];
                *(uint4*)&qs[p][(j * 4 + i) * 8] = v;
            }
        }
    }

    const int nA = n < 16 ? n : 16;
    const int nB = n - 16;
    int iA = start + (ln < nA ? ln : nA - 1);
    int iB = (nB > 0) ? (start + 16 + (ln < nB ? ln : nB - 1)) : iA;
    int eA = csr_e[iA];
    int eB = csr_e[iB];

    const unsigned short* brA = &bbgb[(size_t)eA * 64];
    const unsigned short* brB = &bbgb[(size_t)eB * 64];
    bf16x8 A0a = *(const bf16x8*)&brA[kb];
    bf16x8 A1a = *(const bf16x8*)&brA[32 + kb];
    bf16x8 A0b = *(const bf16x8*)&brB[kb];
    bf16x8 A1b = *(const bf16x8*)&brB[32 + kb];

    bool vA0 = (g4 * 4 + 0) < nA, vA1 = (g4 * 4 + 1) < nA;
    bool vA2 = (g4 * 4 + 2) < nA, vA3 = (g4 * 4 + 3) < nA;
    bool vB0 = (g4 * 4 + 0) < nB, vB1 = (g4 * 4 + 1) < nB;
    bool vB2 = (g4 * 4 + 2) < nB, vB3 = (g4 * 4 + 3) < nB;

    float pv[4];
    #pragma unroll
    for (int f = 0; f < 4; ++f)
        pv[f] = P[(size_t)seg * 1024 + wbase + f * 16 + ln];

    __syncthreads();

    #pragma unroll
    for (int f = 0; f < 4; ++f) {
        int col = wbase + f * 16 + ln;
        int cc = col - cbase;
        const unsigned short* wr = &w1cT[(size_t)col * 64];
        bf16x8 b0 = *(const bf16x8*)&wr[kb];
        bf16x8 b1 = *(const bf16x8*)&wr[32 + kb];
        f32x4 dA = {0.f, 0.f, 0.f, 0.f};
        dA = __builtin_amdgcn_mfma_f32_16x16x32_bf16(A0a, b0, dA, 0, 0, 0);
        dA = __builtin_amdgcn_mfma_f32_16x16x32_bf16(A1a, b1, dA, 0, 0, 0);
        f32x4 dB = {0.f, 0.f, 0.f, 0.f};
        dB = __builtin_amdgcn_mfma_f32_16x16x32_bf16(A0b, b0, dB, 0, 0, 0);
        dB = __builtin_amdgcn_mfma_f32_16x16x32_bf16(A1b, b1, dB, 0, 0, 0);
        float qA0 = bf2f(qs[g4 * 4 + 0][cc]);
        float qA1 = bf2f(qs[g4 * 4 + 1][cc]);
        float qA2 = bf2f(qs[g4 * 4 + 2][cc]);
        float qA3 = bf2f(qs[g4 * 4 + 3][cc]);
        float qB0 = bf2f(qs[16 + g4 * 4 + 0][cc]);
        float qB1 = bf2f(qs[16 + g4 * 4 + 1][cc]);
        float qB2 = bf2f(qs[16 + g4 * 4 + 2][cc]);
        float qB3 = bf2f(qs[16 + g4 * 4 + 3][cc]);
        float h = 0.f;
        h += vA0 ? fmaxf(dA[0] + pv[f] + qA0, 0.f) : 0.f;
        h += vA1 ? fmaxf(dA[1] + pv[f] + qA1, 0.f) : 0.f;
        h += vA2 ? fmaxf(dA[2] + pv[f] + qA2, 0.f) : 0.f;
        h += vA3 ? fmaxf(dA[3] + pv[f] + qA3, 0.f) : 0.f;
        h += vB0 ? fmaxf(dB[0] + pv[f] + qB0, 0.f) : 0.f;
        h += vB1 ? fmaxf(dB[1] + pv[f] + qB1, 0.f) : 0.f;
        h += vB2 ? fmaxf(dB[2] + pv[f] + qB2, 0.f) : 0.f;
        h += vB3 ? fmaxf(dB[3] + pv[f] + qB3, 0.f) : 0.f;
        h += __shfl_xor(h, 16);
        h += __shfl_xor(h, 32);
        if (l < 16) atomicAdd(&HS[(size_t)seg * 1024 + wbase + f * 16 + l], h);
    }
}

// ================= k_out: (feats + HS@W2 + cnt*b2)/(1+cnt) + nt-copy =================
// grid 2176: bid%17==16 -> gemm (128); else copy (2048)
__global__ __launch_bounds__(256) void k_out(const float* __restrict__ HS,
                                             const unsigned short* __restrict__ w2T,
                                             const float* __restrict__ feats,
                                             const float* __restrict__ b2,
                                             const int* __restrict__ counts,
                                             float* __restrict__ out0,
                                             const f32x4* __restrict__ csrc,
                                             f32x4* __restrict__ cdst) {
    int bid = blockIdx.x;
    if ((bid % 17) != 16) { copy_nt(csrc, cdst, OFF_OUT, LEN_OUT, 2048, (bid / 17) * 16 + (bid % 17)); return; }
    int job = bid / 17;
    int m0 = (job >> 3) * 64, n0 = (job & 7) * 64;
    int tid = threadIdx.x, w = tid >> 6, l = tid & 63;
    int ln = l & 15, kb = (l >> 4) * 8;
    int row = m0 + w * 16 + ln;
    f32x4 acc[4] = {};
    for (int k0 = 0; k0 < 1024; k0 += 32) {
        const float* hp = &HS[(size_t)row * 1024 + k0 + kb];
        float4 h0 = *(const float4*)&hp[0];
        float4 h1 = *(const float4*)&hp[4];
        bf16x8 a;
        a[0] = (short)f2bf(h0.x); a[1] = (short)f2bf(h0.y); a[2] = (short)f2bf(h0.z); a[3] = (short)f2bf(h0.w);
        a[4] = (short)f2bf(h1.x); a[5] = (short)f2bf(h1.y); a[6] = (short)f2bf(h1.z); a[7] = (short)f2bf(h1.w);
        #pragma unroll
        for (int f = 0; f < 4; ++f) {
            bf16x8 b = *(const bf16x8*)&w2T[(size_t)(n0 + f * 16 + ln) * 1024 + k0 + kb];
            acc[f] = __builtin_amdgcn_mfma_f32_16x16x32_bf16(a, b, acc[f], 0, 0, 0);
        }
    }
    int mr = m0 + w * 16 + (l >> 4) * 4;
    float cv[4], inv[4];
    #pragma unroll
    for (int r = 0; r < 4; ++r) {
        float c = (float)counts[mr + r];
        cv[r] = c;
        inv[r] = 1.0f / (1.0f + c);
    }
    #pragma unroll
    for (int f = 0; f < 4; ++f) {
        int n = n0 + f * 16 + ln;
        float b2v = b2[n];
        #pragma unroll
        for (int r = 0; r < 4; ++r) {
            float fv = feats[(size_t)(mr + r) * 512 + n];
            out0[(size_t)(mr + r) * 512 + n] = (fv + acc[f][r] + cv[r] * b2v) * inv[r];
        }
    }
}

extern "C" void kernel_launch(void* const* d_in, const int* in_sizes, int n_in,
                              void* d_out, int out_size, void* d_ws, size_t ws_size,
                              hipStream_t stream) {
    const float* feats = (const float*)d_in[0];
    const float* bb    = (const float*)d_in[1];
    const int*   pairs = (const int*)d_in[2];
    const float* W1    = (const float*)d_in[3];
    const float* b1    = (const float*)d_in[4];
    const float* W2    = (const float*)d_in[5];
    const float* b2    = (const float*)d_in[6];

    float* out        = (float*)d_out;
    float* out_feats  = out;
    float* out_bb     = out + (size_t)N_OBJ * 512;
    float* out_pairs  = out + (size_t)N_OBJ * 512 + (size_t)N_OBJ * N_OBJ * 64;

    // ---- workspace layout (~18.6 MB), HS NOT aliased ----
    char* w = (char*)d_ws;
    unsigned short* featsb = (unsigned short*)w;                              // [0,1M)
    unsigned short* w1pqT  = (unsigned short*)(w + (1u << 20));               // [1M,3M)
    unsigned short* w1cT   = (unsigned short*)(w + (3u << 20));               // 128K
    unsigned short* w2T    = (unsigned short*)(w + (3u << 20) + (128u << 10)); // 1M
    float*          HS     = (float*)(w + (4u << 20) + (128u << 10));         // 4M
    float*          P      = (float*)(w + (8u << 20) + (128u << 10));         // 4M
    unsigned short* Qb     = (unsigned short*)(w + (12u << 20) + (128u << 10)); // 2M
    unsigned short* bbgb   = (unsigned short*)(w + (14u << 20) + (128u << 10)); // 4M
    char* ints = w + (18u << 20) + (128u << 10);
    int*      counts  = (int*)ints;
    int*      csr_obj = (int*)(ints + 4096);
    int*      csr_e   = (int*)(ints + 4096 + 131072);
    unsigned* brec    = (unsigned*)(ints + 4096 + 262144);
    int*      bcnt    = (int*)(ints + 4096 + 262144 + 16384);
    int*      rank    = (int*)(ints + 4096 + 262144 + 16384 + 64);

    const f32x4* cbb  = (const f32x4*)bb;
    f32x4*       cobb = (f32x4*)out_bb;

    k_zero<<<1, 256, 0, stream>>>(counts);

    k_a<<<3456, 256, 0, stream>>>(W1, W2, feats, pairs, bb, w1pqT, w1cT, w2T, featsb,
                                  out_pairs, counts, rank, bbgb, (f32x4*)HS, cbb, cobb);
    k_b<<<1923, 256, 0, stream>>>(counts, rank, pairs, csr_obj, csr_e, brec, bcnt,
                                  featsb, w1pqT, b1, P, Qb, cbb, cobb);
    k_seg<<<12288, 256, 0, stream>>>(csr_obj, csr_e, brec, bcnt, bbgb, w1cT, P, Qb, HS,
                                     cbb, cobb);
    k_out<<<2176, 256, 0, stream>>>(HS, w2T, feats, b2, counts, out_feats, cbb, cobb);
}

// Round 16
// 215.813 us; speedup vs baseline: 1.0203x; 1.0203x over previous
//
#include <hip/hip_runtime.h>

#define N_OBJ 1024
#define E_P   32768

typedef float f32x4 __attribute__((ext_vector_type(4)));
typedef short bf16x8 __attribute__((ext_vector_type(8)));
typedef unsigned short u16x4 __attribute__((ext_vector_type(4)));

__device__ __forceinline__ unsigned short f2bf(float f) {
    unsigned u = __float_as_uint(f);
    u = u + 0x7FFFu + ((u >> 16) & 1u);   // RNE
    return (unsigned short)(u >> 16);
}
__device__ __forceinline__ float bf2f(unsigned short u) {
    return __uint_as_float(((unsigned)u) << 16);
}

// ---- copy split (f32x4 units): total = 1024*1024*64/4 = 16777216 ----
#define OFF_A    0
#define LEN_A    5242880
#define OFF_B    (OFF_A + LEN_A)
#define LEN_B    4194304
#define OFF_SEG  (OFF_B + LEN_B)
#define LEN_SEG  4194304
#define OFF_OUT  (OFF_SEG + LEN_SEG)
#define LEN_OUT  3145728

__device__ __forceinline__ void copy_nt(const f32x4* __restrict__ src,
                                        f32x4* __restrict__ dst,
                                        int off, int len, int nb, int cb) {
    int stride = nb * 256;
    int i = off + cb * 256 + threadIdx.x;
    int end = off + len;
    for (; i + 3 * stride < end; i += 4 * stride) {
        f32x4 v0 = __builtin_nontemporal_load(&src[i]);
        f32x4 v1 = __builtin_nontemporal_load(&src[i + stride]);
        f32x4 v2 = __builtin_nontemporal_load(&src[i + 2 * stride]);
        f32x4 v3 = __builtin_nontemporal_load(&src[i + 3 * stride]);
        __builtin_nontemporal_store(v0, &dst[i]);
        __builtin_nontemporal_store(v1, &dst[i + stride]);
        __builtin_nontemporal_store(v2, &dst[i + 2 * stride]);
        __builtin_nontemporal_store(v3, &dst[i + 3 * stride]);
    }
    for (; i < end; i += stride) {
        f32x4 a = __builtin_nontemporal_load(&src[i]);
        __builtin_nontemporal_store(a, &dst[i]);
    }
}

__global__ __launch_bounds__(256) void k_zero(int* __restrict__ counts) {
    ((int4*)counts)[threadIdx.x] = make_int4(0, 0, 0, 0);
}

// ================= k_a: transposes + featsb + pairs/hist/rank + nt-copy =================
// grid 3168: bid%3==2 -> copy (1056); else job = (bid/3)*2 + bid%3 (0..2111)
__global__ __launch_bounds__(256) void k_a(const float* __restrict__ W1,
                                           const float* __restrict__ W2,
                                           const float* __restrict__ feats,
                                           const int* __restrict__ pairs,
                                           unsigned short* __restrict__ w1pqT,
                                           unsigned short* __restrict__ w1cT,
                                           unsigned short* __restrict__ w2T,
                                           unsigned short* __restrict__ featsb,
                                           float* __restrict__ out_pairs,
                                           int* __restrict__ counts,
                                           int* __restrict__ rank,
                                           const f32x4* __restrict__ csrc,
                                           f32x4* __restrict__ cdst) {
    int bid = blockIdx.x, tid = threadIdx.x;
    if ((bid % 3) == 2) { copy_nt(csrc, cdst, OFF_A, LEN_A, 1056, bid / 3); return; }
    int job = (bid / 3) * 2 + (bid % 3);
    if (job >= 1856) {                 // pairs passthrough + histogram + rank
        int i = (job - 1856) * 256 + tid;
        out_pairs[i] = (float)pairs[i];
        if (i < E_P) rank[i] = atomicAdd(&counts[pairs[2 * i]], 1);
        return;
    }
    if (job >= 1600) {                 // featsb straight convert
        int base = (job - 1600) * 2048 + tid * 8;
        float4 v0 = *(const float4*)&feats[base];
        float4 v1 = *(const float4*)&feats[base + 4];
        u16x4 o0 = { f2bf(v0.x), f2bf(v0.y), f2bf(v0.z), f2bf(v0.w) };
        u16x4 o1 = { f2bf(v1.x), f2bf(v1.y), f2bf(v1.z), f2bf(v1.w) };
        *(u16x4*)&featsb[base] = o0;
        *(u16x4*)&featsb[base + 4] = o1;
        return;
    }
    const float* in; unsigned short* out;
    int LDI, LDO, r0, c0, nbase, kbase;
    if (job < 1024) {                  // W1[0:1024] -> w1pqT [2048][512]
        r0 = (job >> 5) * 32; c0 = (job & 31) * 32;
        in = W1; LDI = 1024; out = w1pqT; LDO = 512;
        nbase = c0 + (r0 >= 512 ? 1024 : 0); kbase = r0 & 511;
    } else if (job < 1088) {           // W1[1024:1088] -> w1cT [1024][64]
        int t = job - 1024; r0 = 1024 + (t >> 5) * 32; c0 = (t & 31) * 32;
        in = W1; LDI = 1024; out = w1cT; LDO = 64;
        nbase = c0; kbase = r0 - 1024;
    } else {                           // W2 [1024][512] -> w2T [512][1024]
        int t = job - 1088; r0 = (t >> 4) * 32; c0 = (t & 15) * 32;
        in = W2; LDI = 512; out = w2T; LDO = 1024;
        nbase = c0; kbase = r0;
    }
    __shared__ float lds[32][33];
    int ti = tid >> 3, tj = (tid & 7) * 4;
    float4 v = *(const float4*)&in[(size_t)(r0 + ti) * LDI + c0 + tj];
    lds[ti][tj] = v.x; lds[ti][tj + 1] = v.y; lds[ti][tj + 2] = v.z; lds[ti][tj + 3] = v.w;
    __syncthreads();
    int oc = tid >> 3, oj = (tid & 7) * 4;
    u16x4 o = { f2bf(lds[oj][oc]), f2bf(lds[oj + 1][oc]),
                f2bf(lds[oj + 2][oc]), f2bf(lds[oj + 3][oc]) };
    *(u16x4*)&out[(size_t)(nbase + oc) * LDO + kbase + oj] = o;
}

// ================= k_b: offsets-store + scatter(csr_obj + bbgc) + PQ GEMM + nt-copy =================
// grid 1923: bid%3<2 -> copy (1282); bid%3==2 -> role = bid/3 (0..640):
//   role 0 = offsets store; 1..128 = scatter+bbgc; 129..640 = GEMM
__global__ __launch_bounds__(256) void k_b(const int* __restrict__ counts,
                                           const int* __restrict__ rank,
                                           const int* __restrict__ pairs,
                                           const float* __restrict__ bb,
                                           int* __restrict__ csr_obj,
                                           unsigned short* __restrict__ bbgc,
                                           int* __restrict__ offsets,
                                           const unsigned short* __restrict__ featsb,
                                           const unsigned short* __restrict__ w1pqT,
                                           const float* __restrict__ b1,
                                           float* __restrict__ P,
                                           unsigned short* __restrict__ Qb,
                                           const f32x4* __restrict__ csrc,
                                           f32x4* __restrict__ cdst) {
    int bid = blockIdx.x, tid = threadIdx.x;
    if ((bid % 3) < 2) { copy_nt(csrc, cdst, OFF_B, LEN_B, 1282, (bid / 3) * 2 + (bid % 3)); return; }
    int role = bid / 3;

    if (role >= 129) {                 // ---- PQ GEMM tile ----
        int job = role - 129;
        int m0 = (job >> 5) * 64, n0 = (job & 31) * 64;
        int w = tid >> 6, l = tid & 63;
        int ln = l & 15, kb = (l >> 4) * 8;
        int row = m0 + w * 16 + ln;
        f32x4 acc[4] = {};
        for (int k0 = 0; k0 < 512; k0 += 32) {
            bf16x8 a = *(const bf16x8*)&featsb[(size_t)row * 512 + k0 + kb];
            #pragma unroll
            for (int f = 0; f < 4; ++f) {
                bf16x8 b = *(const bf16x8*)&w1pqT[(size_t)(n0 + f * 16 + ln) * 512 + k0 + kb];
                acc[f] = __builtin_amdgcn_mfma_f32_16x16x32_bf16(a, b, acc[f], 0, 0, 0);
            }
        }
        int mr = m0 + w * 16 + (l >> 4) * 4;
        if (n0 < 1024) {
            #pragma unroll
            for (int f = 0; f < 4; ++f) {
                int n = n0 + f * 16 + ln;
                float b1v = b1[n];
                #pragma unroll
                for (int r = 0; r < 4; ++r)
                    P[(size_t)(mr + r) * 1024 + n] = acc[f][r] + b1v;
            }
        } else {
            #pragma unroll
            for (int f = 0; f < 4; ++f) {
                int n = n0 - 1024 + f * 16 + ln;
                #pragma unroll
                for (int r = 0; r < 4; ++r)
                    Qb[(size_t)(mr + r) * 1024 + n] = f2bf(acc[f][r]);
            }
        }
        return;
    }

    // ---- roles 0..128: redundant exclusive scan of counts in LDS ----
    __shared__ int sbuf[2][256];
    __shared__ int soff[1024];
    int c[4]; int s = 0;
    #pragma unroll
    for (int i = 0; i < 4; ++i) { c[i] = counts[tid * 4 + i]; s += c[i]; }
    sbuf[0][tid] = s;
    __syncthreads();
    int sel = 0;
    for (int d = 1; d < 256; d <<= 1) {
        int v = sbuf[sel][tid];
        if (tid >= d) v += sbuf[sel][tid - d];
        sbuf[sel ^ 1][tid] = v;
        sel ^= 1;
        __syncthreads();
    }
    int base = sbuf[sel][tid] - s;
    int run = base;
    #pragma unroll
    for (int i = 0; i < 4; ++i) { soff[tid * 4 + i] = run; run += c[i]; }
    __syncthreads();

    if (role == 0) {                   // ---- offsets store ----
        #pragma unroll
        for (int i = 0; i < 4; ++i) offsets[tid * 4 + i] = soff[tid * 4 + i];
        return;
    }

    // ---- scatter: csr_obj[pos] + bbgc[pos] (bf16 CSR-ordered bb rows) ----
    int e = (role - 1) * 256 + tid;
    int sub = pairs[2 * e];
    int obj = pairs[2 * e + 1];
    int pos = soff[sub] + rank[e];
    csr_obj[pos] = obj;
    const f32x4* src = (const f32x4*)&bb[((size_t)sub * 1024 + (size_t)obj) * 64];
    u16x4* dst = (u16x4*)&bbgc[(size_t)pos * 64];
    #pragma unroll
    for (int i = 0; i < 16; ++i) {
        f32x4 v = __builtin_nontemporal_load(&src[i]);
        u16x4 o = { f2bf(v.x), f2bf(v.y), f2bf(v.z), f2bf(v.w) };
        dst[i] = o;
    }
}

// ================= k_seg: seg-owned blocks, atomic-free, XCD-pinned quarters =================
// grid 6144 = 8*768. x=bid&7 (XCD), k=bid>>3.
//   k<512: compute, quarter qd=x>>1, seg = k*2+(x&1)
//   k>=512: copy cb=(k-512)*8+x (2048 blocks)
__global__ __launch_bounds__(256) void k_seg(const int* __restrict__ csr_obj,
                                             const int* __restrict__ offsets,
                                             const int* __restrict__ counts,
                                             const unsigned short* __restrict__ bbgc,
                                             const unsigned short* __restrict__ w1cT,
                                             const float* __restrict__ P,
                                             const unsigned short* __restrict__ Qb,
                                             float* __restrict__ HS,
                                             const f32x4* __restrict__ csrc,
                                             f32x4* __restrict__ cdst) {
    int bid = blockIdx.x, tid = threadIdx.x;
    int x = bid & 7, k = bid >> 3;
    if (k >= 512) { copy_nt(csrc, cdst, OFF_SEG, LEN_SEG, 2048, (k - 512) * 8 + x); return; }
    const int qd = x >> 1;
    const int seg = k * 2 + (x & 1);
    const int start = offsets[seg];
    const int n = counts[seg];

    const int w = tid >> 6, l = tid & 63;
    const int ln = l & 15, g4 = l >> 4, kb = g4 * 8;
    const int cbase = qd * 256;
    const int wbase = cbase + w * 64;

    __shared__ unsigned short qs[32][264];

    float pv[4];
    #pragma unroll
    for (int f = 0; f < 4; ++f)
        pv[f] = P[(size_t)seg * 1024 + wbase + f * 16 + ln];

    float hpart[4] = {0.f, 0.f, 0.f, 0.f};

    for (int c0 = 0; c0 < n; c0 += 32) {
        int m = n - c0; if (m > 32) m = 32;
        const int mA = m < 16 ? m : 16;
        const int mB = m - 16;

        __syncthreads();   // protect qs from previous chunk's readers
        {
            int p = tid >> 3, j = tid & 7;
            if (p < m) {
                int op = csr_obj[start + c0 + p];
                const uint4* qrow = (const uint4*)&Qb[(size_t)op * 1024 + cbase];
                #pragma unroll
                for (int i = 0; i < 4; ++i) {
                    uint4 v = qrow[j * 4 + i];
                    *(uint4*)&qs[p][(j * 4 + i) * 8] = v;
                }
            }
        }

        int iA = start + c0 + (ln < mA ? ln : mA - 1);
        int iB = (mB > 0) ? (start + c0 + 16 + (ln < mB ? ln : mB - 1)) : iA;
        const unsigned short* brA = &bbgc[(size_t)iA * 64];
        const unsigned short* brB = &bbgc[(size_t)iB * 64];
        bf16x8 A0a = *(const bf16x8*)&brA[kb];
        bf16x8 A1a = *(const bf16x8*)&brA[32 + kb];
        bf16x8 A0b = *(const bf16x8*)&brB[kb];
        bf16x8 A1b = *(const bf16x8*)&brB[32 + kb];

        bool vA0 = (g4 * 4 + 0) < mA, vA1 = (g4 * 4 + 1) < mA;
        bool vA2 = (g4 * 4 + 2) < mA, vA3 = (g4 * 4 + 3) < mA;
        bool vB0 = (g4 * 4 + 0) < mB, vB1 = (g4 * 4 + 1) < mB;
        bool vB2 = (g4 * 4 + 2) < mB, vB3 = (g4 * 4 + 3) < mB;

        __syncthreads();   // qs ready

        #pragma unroll
        for (int f = 0; f < 4; ++f) {
            int col = wbase + f * 16 + ln;
            int cc = col - cbase;
            const unsigned short* wr = &w1cT[(size_t)col * 64];
            bf16x8 b0 = *(const bf16x8*)&wr[kb];
            bf16x8 b1 = *(const bf16x8*)&wr[32 + kb];
            f32x4 dA = {0.f, 0.f, 0.f, 0.f};
            dA = __builtin_amdgcn_mfma_f32_16x16x32_bf16(A0a, b0, dA, 0, 0, 0);
            dA = __builtin_amdgcn_mfma_f32_16x16x32_bf16(A1a, b1, dA, 0, 0, 0);
            f32x4 dB = {0.f, 0.f, 0.f, 0.f};
            dB = __builtin_amdgcn_mfma_f32_16x16x32_bf16(A0b, b0, dB, 0, 0, 0);
            dB = __builtin_amdgcn_mfma_f32_16x16x32_bf16(A1b, b1, dB, 0, 0, 0);
            float qA0 = bf2f(qs[g4 * 4 + 0][cc]);
            float qA1 = bf2f(qs[g4 * 4 + 1][cc]);
            float qA2 = bf2f(qs[g4 * 4 + 2][cc]);
            float qA3 = bf2f(qs[g4 * 4 + 3][cc]);
            float qB0 = bf2f(qs[16 + g4 * 4 + 0][cc]);
            float qB1 = bf2f(qs[16 + g4 * 4 + 1][cc]);
            float qB2 = bf2f(qs[16 + g4 * 4 + 2][cc]);
            float qB3 = bf2f(qs[16 + g4 * 4 + 3][cc]);
            float h = 0.f;
            h += vA0 ? fmaxf(dA[0] + pv[f] + qA0, 0.f) : 0.f;
            h += vA1 ? fmaxf(dA[1] + pv[f] + qA1, 0.f) : 0.f;
            h += vA2 ? fmaxf(dA[2] + pv[f] + qA2, 0.f) : 0.f;
            h += vA3 ? fmaxf(dA[3] + pv[f] + qA3, 0.f) : 0.f;
            h += vB0 ? fmaxf(dB[0] + pv[f] + qB0, 0.f) : 0.f;
            h += vB1 ? fmaxf(dB[1] + pv[f] + qB1, 0.f) : 0.f;
            h += vB2 ? fmaxf(dB[2] + pv[f] + qB2, 0.f) : 0.f;
            h += vB3 ? fmaxf(dB[3] + pv[f] + qB3, 0.f) : 0.f;
            hpart[f] += h;
        }
    }

    #pragma unroll
    for (int f = 0; f < 4; ++f) {
        float h = hpart[f];
        h += __shfl_xor(h, 16);
        h += __shfl_xor(h, 32);
        if (l < 16) HS[(size_t)seg * 1024 + wbase + f * 16 + l] = h;
    }
}

// ================= k_out: (feats + HS@W2 + cnt*b2)/(1+cnt) + nt-copy =================
// grid 2176: bid%17==16 -> gemm (128); else copy (2048)
__global__ __launch_bounds__(256) void k_out(const float* __restrict__ HS,
                                             const unsigned short* __restrict__ w2T,
                                             const float* __restrict__ feats,
                                             const float* __restrict__ b2,
                                             const int* __restrict__ counts,
                                             float* __restrict__ out0,
                                             const f32x4* __restrict__ csrc,
                                             f32x4* __restrict__ cdst) {
    int bid = blockIdx.x;
    if ((bid % 17) != 16) { copy_nt(csrc, cdst, OFF_OUT, LEN_OUT, 2048, (bid / 17) * 16 + (bid % 17)); return; }
    int job = bid / 17;
    int m0 = (job >> 3) * 64, n0 = (job & 7) * 64;
    int tid = threadIdx.x, w = tid >> 6, l = tid & 63;
    int ln = l & 15, kb = (l >> 4) * 8;
    int row = m0 + w * 16 + ln;
    f32x4 acc[4] = {};
    for (int k0 = 0; k0 < 1024; k0 += 32) {
        const float* hp = &HS[(size_t)row * 1024 + k0 + kb];
        float4 h0 = *(const float4*)&hp[0];
        float4 h1 = *(const float4*)&hp[4];
        bf16x8 a;
        a[0] = (short)f2bf(h0.x); a[1] = (short)f2bf(h0.y); a[2] = (short)f2bf(h0.z); a[3] = (short)f2bf(h0.w);
        a[4] = (short)f2bf(h1.x); a[5] = (short)f2bf(h1.y); a[6] = (short)f2bf(h1.z); a[7] = (short)f2bf(h1.w);
        #pragma unroll
        for (int f = 0; f < 4; ++f) {
            bf16x8 b = *(const bf16x8*)&w2T[(size_t)(n0 + f * 16 + ln) * 1024 + k0 + kb];
            acc[f] = __builtin_amdgcn_mfma_f32_16x16x32_bf16(a, b, acc[f], 0, 0, 0);
        }
    }
    int mr = m0 + w * 16 + (l >> 4) * 4;
    float cv[4], inv[4];
    #pragma unroll
    for (int r = 0; r < 4; ++r) {
        float c = (float)counts[mr + r];
        cv[r] = c;
        inv[r] = 1.0f / (1.0f + c);
    }
    #pragma unroll
    for (int f = 0; f < 4; ++f) {
        int n = n0 + f * 16 + ln;
        float b2v = b2[n];
        #pragma unroll
        for (int r = 0; r < 4; ++r) {
            float fv = feats[(size_t)(mr + r) * 512 + n];
            out0[(size_t)(mr + r) * 512 + n] = (fv + acc[f][r] + cv[r] * b2v) * inv[r];
        }
    }
}

extern "C" void kernel_launch(void* const* d_in, const int* in_sizes, int n_in,
                              void* d_out, int out_size, void* d_ws, size_t ws_size,
                              hipStream_t stream) {
    const float* feats = (const float*)d_in[0];
    const float* bb    = (const float*)d_in[1];
    const int*   pairs = (const int*)d_in[2];
    const float* W1    = (const float*)d_in[3];
    const float* b1    = (const float*)d_in[4];
    const float* W2    = (const float*)d_in[5];
    const float* b2    = (const float*)d_in[6];

    float* out        = (float*)d_out;
    float* out_feats  = out;
    float* out_bb     = out + (size_t)N_OBJ * 512;
    float* out_pairs  = out + (size_t)N_OBJ * 512 + (size_t)N_OBJ * N_OBJ * 64;

    // ---- workspace layout (~19 MB) ----
    char* w = (char*)d_ws;
    unsigned short* featsb = (unsigned short*)w;                              // [0,1M)
    unsigned short* w1pqT  = (unsigned short*)(w + (1u << 20));               // [1M,3M)
    unsigned short* w1cT   = (unsigned short*)(w + (3u << 20));               // 128K
    unsigned short* w2T    = (unsigned short*)(w + (3u << 20) + (128u << 10)); // 1M
    float*          HS     = (float*)(w + (4u << 20) + (128u << 10));         // 4M
    float*          P      = (float*)(w + (8u << 20) + (128u << 10));         // 4M
    unsigned short* Qb     = (unsigned short*)(w + (12u << 20) + (128u << 10)); // 2M
    unsigned short* bbgc   = (unsigned short*)(w + (14u << 20) + (128u << 10)); // 4M
    char* ints = w + (18u << 20) + (128u << 10);
    int*      counts  = (int*)ints;                       // 4 KB
    int*      offsets = (int*)(ints + 4096);              // 4 KB
    int*      csr_obj = (int*)(ints + 8192);              // 128 KB
    int*      rank    = (int*)(ints + 8192 + 131072);     // 128 KB

    const f32x4* cbb  = (const f32x4*)bb;
    f32x4*       cobb = (f32x4*)out_bb;

    k_zero<<<1, 256, 0, stream>>>(counts);

    k_a<<<3168, 256, 0, stream>>>(W1, W2, feats, pairs, w1pqT, w1cT, w2T, featsb,
                                  out_pairs, counts, rank, cbb, cobb);
    k_b<<<1923, 256, 0, stream>>>(counts, rank, pairs, bb, csr_obj, bbgc, offsets,
                                  featsb, w1pqT, b1, P, Qb, cbb, cobb);
    k_seg<<<6144, 256, 0, stream>>>(csr_obj, offsets, counts, bbgc, w1cT, P, Qb, HS,
                                    cbb, cobb);
    k_out<<<2176, 256, 0, stream>>>(HS, w2T, feats, b2, counts, out_feats, cbb, cobb);
}